// Round 5
// baseline (287.023 us; speedup 1.0000x reference)
//
#include <hip/hip_runtime.h>

// HEAT layer with sorted timestamps — single-pass decoupled-lookback scan.
//   out[i] = P_inc[i] + eps*exp(beta*t_i) * Q_inc[i]   (+ duplicate-t fixup)
//   P_inc[i] = sum_{j<=i} h[j],  Q_inc[i] = sum_{j<=i} relu(h[j])*exp(-beta*t_j)
// Rows j>i with t[j]==t[i] contribute h[j] + eps*relu(h[j]) exactly
// (exp(beta*0)=1) -> rare in-kernel forward fixup.
//
// One block per (chunk c, column-group g). h slice lives in registers across
// the whole block lifetime: publish chunk aggregate -> decoupled lookback for
// the exclusive prefix -> emit out. h is read from HBM exactly once.
// flags[chain]: 0 = not ready, 1 = aggregate ready, 2 = inclusive ready.
// Agent-scope release/acquire handles cross-XCD L2 non-coherence.

namespace {
constexpr int S   = 8192;
constexpr int D   = 768;
constexpr int DV  = D / 4;       // 192 float4 per row
constexpr int CH  = 32;          // rows per chunk
constexpr int NC  = S / CH;      // 256 chunks
constexpr int QL  = 64;          // float4-columns per block
constexpr int NG  = DV / QL;     // 3 column groups
constexpr int RG  = 4;           // row-groups per chunk
constexpr int RR  = CH / RG;     // 8 rows per row-group
constexpr int NCHAIN = NG * NC;  // 768 lookback cells
}

__device__ __forceinline__ float4 f4add(float4 a, float4 b) {
    return make_float4(a.x + b.x, a.y + b.y, a.z + b.z, a.w + b.w);
}
__device__ __forceinline__ void f4relu_fma(float4& acc, float4 h, float d) {
    acc.x += fmaxf(h.x, 0.f) * d;
    acc.y += fmaxf(h.y, 0.f) * d;
    acc.z += fmaxf(h.z, 0.f) * d;
    acc.w += fmaxf(h.w, 0.f) * d;
}

__global__ __launch_bounds__(256)
void heat_zero_flags(int* __restrict__ flags) {
    int i = blockIdx.x * 256 + threadIdx.x;
    if (i < NCHAIN) flags[i] = 0;
}

__global__ __launch_bounds__(256)
void heat_onepass(const float* __restrict__ h, const float* __restrict__ t,
                  const float* __restrict__ epsp, const float* __restrict__ betap,
                  int* __restrict__ flags,
                  float4* __restrict__ aggP, float4* __restrict__ aggQ,
                  float4* __restrict__ incP, float4* __restrict__ incQ,
                  float* __restrict__ out) {
    const int tid  = threadIdx.x;
    const int lane = tid & (QL - 1);
    const int r    = tid >> 6;           // row-group (one wave each)
    const int c    = blockIdx.x;         // chunk (lookback chain dimension)
    const int g    = blockIdx.y;         // column group
    const int q    = g * QL + lane;
    const float eps = epsp[0], beta = betap[0];

    __shared__ float tt[CH + 1];
    __shared__ float dec[CH], epv[CH];
    __shared__ float4 rgP[RG][QL], rgQ[RG][QL];
    __shared__ float4 prefP[QL], prefQ[QL];

    const float4* h4   = (const float4*)h;
    float4*       out4 = (float4*)out;
    const int row0 = c * CH + r * RR;

    // Issue the h loads first; everything else hides under them.
    float4 hv[RR];
#pragma unroll
    for (int k = 0; k < RR; ++k) hv[k] = h4[(size_t)(row0 + k) * DV + q];

    if (tid <= CH) {
        int j = c * CH + tid;
        tt[tid] = (j < S) ? t[j] : 1e30f;    // sentinel past the end
    }
    __syncthreads();
    if (tid < CH) {
        float tv = tt[tid];
        dec[tid] = expf(-beta * tv);
        epv[tid] = eps * expf(beta * tv);
    }
    __syncthreads();

    float4 pp = {0, 0, 0, 0}, qq = {0, 0, 0, 0};
#pragma unroll
    for (int k = 0; k < RR; ++k) {
        pp = f4add(pp, hv[k]);
        f4relu_fma(qq, hv[k], dec[r * RR + k]);
    }
    rgP[r][lane] = pp;
    rgQ[r][lane] = qq;
    __syncthreads();

    const int chain = g * NC + c;
    const float4 z = {0, 0, 0, 0};

    if (c == 0) {
        if (r == 0) {
            float4 tp = f4add(f4add(rgP[0][lane], rgP[1][lane]),
                              f4add(rgP[2][lane], rgP[3][lane]));
            incP[chain * QL + lane] = tp;
            prefP[lane] = z;
        } else if (r == 1) {
            float4 tq = f4add(f4add(rgQ[0][lane], rgQ[1][lane]),
                              f4add(rgQ[2][lane], rgQ[3][lane]));
            incQ[chain * QL + lane] = tq;
            prefQ[lane] = z;
        }
        __syncthreads();   // drains the inc stores of all waves
        if (tid == 0)
            __hip_atomic_store(&flags[chain], 2, __ATOMIC_RELEASE,
                               __HIP_MEMORY_SCOPE_AGENT);
    } else {
        float4 tot = z;
        if (r == 0) {
            tot = f4add(f4add(rgP[0][lane], rgP[1][lane]),
                        f4add(rgP[2][lane], rgP[3][lane]));
            aggP[chain * QL + lane] = tot;
        } else if (r == 1) {
            tot = f4add(f4add(rgQ[0][lane], rgQ[1][lane]),
                        f4add(rgQ[2][lane], rgQ[3][lane]));
            aggQ[chain * QL + lane] = tot;
        }
        __syncthreads();   // drains the agg stores of all waves
        if (tid == 0)
            __hip_atomic_store(&flags[chain], 1, __ATOMIC_RELEASE,
                               __HIP_MEMORY_SCOPE_AGENT);

        if (r < 2) {       // wave 0: P lookback, wave 1: Q lookback
            const float4* aggA = (r == 0) ? aggP : aggQ;
            float4*       incA = (r == 0) ? incP : incQ;
            float4 run = z;
            int p = c - 1;
            while (true) {
                int f;
                do {
                    f = (lane == 0)
                        ? __hip_atomic_load(&flags[g * NC + p], __ATOMIC_ACQUIRE,
                                            __HIP_MEMORY_SCOPE_AGENT)
                        : 0;
                    f = __shfl(f, 0);
                } while (f == 0);
                if (f == 2) { run = f4add(run, incA[(g * NC + p) * QL + lane]); break; }
                run = f4add(run, aggA[(g * NC + p) * QL + lane]);
                --p;       // chain cell 0 always has flag==2 -> p never < 0
            }
            incA[chain * QL + lane] = f4add(run, tot);
            if (r == 0) prefP[lane] = run; else prefQ[lane] = run;
        }
        __syncthreads();   // drains inc stores + makes prefP/prefQ visible
        if (tid == 0)
            __hip_atomic_store(&flags[chain], 2, __ATOMIC_RELEASE,
                               __HIP_MEMORY_SCOPE_AGENT);
    }

    // ---- emit out straight from registers ----
    float4 po = prefP[lane];
    float4 qo = prefQ[lane];
#pragma unroll
    for (int rr2 = 0; rr2 < RG - 1; ++rr2)
        if (rr2 < r) {
            po = f4add(po, rgP[rr2][lane]);
            qo = f4add(qo, rgQ[rr2][lane]);
        }
#pragma unroll
    for (int k = 0; k < RR; ++k) {
        po = f4add(po, hv[k]);
        f4relu_fma(qo, hv[k], dec[r * RR + k]);
        const float ep = epv[r * RR + k];
        float4 o;
        o.x = po.x + ep * qo.x;
        o.y = po.y + ep * qo.y;
        o.z = po.z + ep * qo.z;
        o.w = po.w + ep * qo.w;
        const int lr = r * RR + k;
        if (tt[lr + 1] == tt[lr]) {          // rare: duplicate-timestamp run
            int j = row0 + k + 1;
            const float tcur = tt[lr];
            float tj = tt[lr + 1];
            while (tj == tcur) {
                float4 hj = h4[(size_t)j * DV + q];
                o.x += hj.x + eps * fmaxf(hj.x, 0.f);
                o.y += hj.y + eps * fmaxf(hj.y, 0.f);
                o.z += hj.z + eps * fmaxf(hj.z, 0.f);
                o.w += hj.w + eps * fmaxf(hj.w, 0.f);
                ++j;
                if (j >= S) break;
                const int lj = j - c * CH;
                tj = (lj <= CH) ? tt[lj] : t[j];
            }
        }
        out4[(size_t)(row0 + k) * DV + q] = o;
    }
}

extern "C" void kernel_launch(void* const* d_in, const int* in_sizes, int n_in,
                              void* d_out, int out_size, void* d_ws, size_t ws_size,
                              hipStream_t stream) {
    const float* h    = (const float*)d_in[0];
    const float* t    = (const float*)d_in[1];
    const float* eps  = (const float*)d_in[2];
    const float* beta = (const float*)d_in[3];
    float* out = (float*)d_out;

    int* flags   = (int*)d_ws;                        // NCHAIN ints (pad to 4KB)
    float4* aggP = (float4*)((char*)d_ws + 4096);     // NCHAIN*QL each (~768KB)
    float4* aggQ = aggP + (size_t)NCHAIN * QL;
    float4* incP = aggQ + (size_t)NCHAIN * QL;
    float4* incQ = incP + (size_t)NCHAIN * QL;

    heat_zero_flags<<<(NCHAIN + 255) / 256, 256, 0, stream>>>(flags);
    heat_onepass<<<dim3(NC, NG), 256, 0, stream>>>(h, t, eps, beta, flags,
                                                   aggP, aggQ, incP, incQ, out);
}

// Round 6
// 66.727 us; speedup vs baseline: 4.3014x; 4.3014x over previous
//
#include <hip/hip_runtime.h>

// HEAT layer with sorted timestamps — single-pass scan, parallel-wait +
// redundant batched reduction (no serial lookback).
//   out[i] = P_inc[i] + eps*exp(beta*t_i) * Q_inc[i]   (+ duplicate-t fixup)
//   P_inc[i] = sum_{j<=i} h[j],  Q_inc[i] = sum_{j<=i} relu(h[j])*exp(-beta*t_j)
// Rows j>i with t[j]==t[i] contribute h[j] + eps*relu(h[j]) exactly.
//
// One block per (chunk c, column-group g); h slice lives in registers for the
// whole block lifetime (read from HBM exactly once). Each block publishes its
// chunk aggregate with an agent-release flag; then all lanes poll ALL
// predecessor flags in parallel, and the exclusive prefix is a 4-wave
// strided batched reduction over predecessor aggregates (<=127 terms, L2-hot).

namespace {
constexpr int S   = 8192;
constexpr int D   = 768;
constexpr int DV  = D / 4;       // 192 float4 per row
constexpr int CH  = 64;          // rows per chunk
constexpr int NC  = S / CH;      // 128 chunks (chain length)
constexpr int QL  = 64;          // float4-columns per block
constexpr int NG  = DV / QL;     // 3 column groups
constexpr int RG  = 4;           // row-groups (waves) per block
constexpr int RR  = CH / RG;     // 16 rows per wave
constexpr int NCHAIN = NG * NC;  // 384 chain cells
}

__device__ __forceinline__ float4 f4add(float4 a, float4 b) {
    return make_float4(a.x + b.x, a.y + b.y, a.z + b.z, a.w + b.w);
}
__device__ __forceinline__ void f4relu_fma(float4& acc, float4 h, float d) {
    acc.x += fmaxf(h.x, 0.f) * d;
    acc.y += fmaxf(h.y, 0.f) * d;
    acc.z += fmaxf(h.z, 0.f) * d;
    acc.w += fmaxf(h.w, 0.f) * d;
}

__global__ __launch_bounds__(256)
void heat_zero_flags(int* __restrict__ flags) {
    int i = blockIdx.x * 256 + threadIdx.x;
    if (i < NCHAIN) flags[i] = 0;
}

__global__ __launch_bounds__(256)
void heat_onepass(const float* __restrict__ h, const float* __restrict__ t,
                  const float* __restrict__ epsp, const float* __restrict__ betap,
                  int* __restrict__ flags,
                  float4* __restrict__ aggP, float4* __restrict__ aggQ,
                  float* __restrict__ out) {
    const int tid  = threadIdx.x;
    const int lane = tid & (QL - 1);
    const int r    = tid >> 6;           // wave index 0..3
    const int c    = blockIdx.x;         // chunk
    const int g    = blockIdx.y;         // column group
    const int q    = g * QL + lane;
    const float eps = epsp[0], beta = betap[0];

    __shared__ float tt[CH + 1];
    __shared__ float dec[CH], epv[CH];
    __shared__ float4 rgP[RG][QL], rgQ[RG][QL];
    __shared__ float4 redP[RG][QL], redQ[RG][QL];
    __shared__ float4 prefP[QL], prefQ[QL];

    const float4* h4   = (const float4*)h;
    float4*       out4 = (float4*)out;
    const int row0 = c * CH + r * RR;

    // Issue the h loads first; staging hides under them.
    float4 hv[RR];
#pragma unroll
    for (int k = 0; k < RR; ++k) hv[k] = h4[(size_t)(row0 + k) * DV + q];

    if (tid <= CH) {
        int j = c * CH + tid;
        tt[tid] = (j < S) ? t[j] : 1e30f;    // sentinel past the end
    }
    __syncthreads();
    if (tid < CH) {
        float tv = tt[tid];
        dec[tid] = expf(-beta * tv);
        epv[tid] = eps * expf(beta * tv);
    }
    __syncthreads();

    float4 pp = {0, 0, 0, 0}, qq = {0, 0, 0, 0};
#pragma unroll
    for (int k = 0; k < RR; ++k) {
        pp = f4add(pp, hv[k]);
        f4relu_fma(qq, hv[k], dec[r * RR + k]);
    }
    rgP[r][lane] = pp;
    rgQ[r][lane] = qq;
    __syncthreads();

    const int chain = g * NC + c;
    const float4 z = {0, 0, 0, 0};

    // Publish chunk aggregate (waves 0/1), then one agent-release flag.
    if (r == 0)
        aggP[chain * QL + lane] = f4add(f4add(rgP[0][lane], rgP[1][lane]),
                                        f4add(rgP[2][lane], rgP[3][lane]));
    else if (r == 1)
        aggQ[chain * QL + lane] = f4add(f4add(rgQ[0][lane], rgQ[1][lane]),
                                        f4add(rgQ[2][lane], rgQ[3][lane]));
    __syncthreads();   // drains agg stores (vmcnt) before the flag
    if (tid == 0)
        __hip_atomic_store(&flags[chain], 1, __ATOMIC_RELEASE,
                           __HIP_MEMORY_SCOPE_AGENT);

    if (c > 0) {
        // Parallel wait: each lane owns <=2 predecessor flags.
        const int p1 = lane, p2 = lane + QL;
        for (;;) {
            int f1 = (p1 < c) ? __hip_atomic_load(&flags[g * NC + p1],
                                                  __ATOMIC_ACQUIRE,
                                                  __HIP_MEMORY_SCOPE_AGENT) : 1;
            int f2 = (p2 < c) ? __hip_atomic_load(&flags[g * NC + p2],
                                                  __ATOMIC_ACQUIRE,
                                                  __HIP_MEMORY_SCOPE_AGENT) : 1;
            if (__all(f1 && f2)) break;
        }
        // Redundant exclusive-prefix reduction, 4 waves striped by p%4,
        // 8-deep batched loads (16 in flight per thread).
        float4 aP = z, aQ = z;
        int p = r;
        for (; p + 32 <= c; p += 32) {
            float4 vP[8], vQ[8];
#pragma unroll
            for (int u = 0; u < 8; ++u)
                vP[u] = aggP[((size_t)g * NC + p + 4 * u) * QL + lane];
#pragma unroll
            for (int u = 0; u < 8; ++u)
                vQ[u] = aggQ[((size_t)g * NC + p + 4 * u) * QL + lane];
#pragma unroll
            for (int u = 0; u < 8; ++u) { aP = f4add(aP, vP[u]); aQ = f4add(aQ, vQ[u]); }
        }
        for (; p < c; p += 4) {
            aP = f4add(aP, aggP[((size_t)g * NC + p) * QL + lane]);
            aQ = f4add(aQ, aggQ[((size_t)g * NC + p) * QL + lane]);
        }
        redP[r][lane] = aP;
        redQ[r][lane] = aQ;
        __syncthreads();
        if (r == 0)
            prefP[lane] = f4add(f4add(redP[0][lane], redP[1][lane]),
                                f4add(redP[2][lane], redP[3][lane]));
        else if (r == 1)
            prefQ[lane] = f4add(f4add(redQ[0][lane], redQ[1][lane]),
                                f4add(redQ[2][lane], redQ[3][lane]));
        __syncthreads();
    } else {
        if (r == 0) prefP[lane] = z;
        else if (r == 1) prefQ[lane] = z;
        __syncthreads();
    }

    // ---- emit out straight from registers ----
    float4 po = prefP[lane];
    float4 qo = prefQ[lane];
#pragma unroll
    for (int rr2 = 0; rr2 < RG - 1; ++rr2)
        if (rr2 < r) {
            po = f4add(po, rgP[rr2][lane]);
            qo = f4add(qo, rgQ[rr2][lane]);
        }
#pragma unroll
    for (int k = 0; k < RR; ++k) {
        po = f4add(po, hv[k]);
        f4relu_fma(qo, hv[k], dec[r * RR + k]);
        const float ep = epv[r * RR + k];
        float4 o;
        o.x = po.x + ep * qo.x;
        o.y = po.y + ep * qo.y;
        o.z = po.z + ep * qo.z;
        o.w = po.w + ep * qo.w;
        const int lr = r * RR + k;
        if (tt[lr + 1] == tt[lr]) {          // rare: duplicate-timestamp run
            int j = row0 + k + 1;
            const float tcur = tt[lr];
            float tj = tt[lr + 1];
            while (tj == tcur) {
                float4 hj = h4[(size_t)j * DV + q];
                o.x += hj.x + eps * fmaxf(hj.x, 0.f);
                o.y += hj.y + eps * fmaxf(hj.y, 0.f);
                o.z += hj.z + eps * fmaxf(hj.z, 0.f);
                o.w += hj.w + eps * fmaxf(hj.w, 0.f);
                ++j;
                if (j >= S) break;
                const int lj = j - c * CH;
                tj = (lj <= CH) ? tt[lj] : t[j];
            }
        }
        out4[(size_t)(row0 + k) * DV + q] = o;
    }
}

extern "C" void kernel_launch(void* const* d_in, const int* in_sizes, int n_in,
                              void* d_out, int out_size, void* d_ws, size_t ws_size,
                              hipStream_t stream) {
    const float* h    = (const float*)d_in[0];
    const float* t    = (const float*)d_in[1];
    const float* eps  = (const float*)d_in[2];
    const float* beta = (const float*)d_in[3];
    float* out = (float*)d_out;

    int* flags   = (int*)d_ws;                        // NCHAIN ints (pad to 4KB)
    float4* aggP = (float4*)((char*)d_ws + 4096);     // NCHAIN*QL each (384KB)
    float4* aggQ = aggP + (size_t)NCHAIN * QL;

    heat_zero_flags<<<(NCHAIN + 255) / 256, 256, 0, stream>>>(flags);
    heat_onepass<<<dim3(NC, NG), 256, 0, stream>>>(h, t, eps, beta, flags,
                                                   aggP, aggQ, out);
}

// Round 7
// 31.715 us; speedup vs baseline: 9.0501x; 2.1040x over previous
//
#include <hip/hip_runtime.h>

// HEAT layer with sorted timestamps — two plain kernels, no atomics.
//   out[i] = P_inc[i] + eps*exp(beta*t_i) * Q_inc[i]   (+ duplicate-t fixup)
//   P_inc[i] = sum_{j<=i} h[j],  Q_inc[i] = sum_{j<=i} relu(h[j])*exp(-beta*t_j)
// Rows j>i with t[j]==t[i] contribute h[j] + eps*relu(h[j]) exactly
// (exp(beta*0)=1) -> rare in-kernel forward fixup.
//
// Lesson from rounds 5/6: intra-kernel cross-XCD flag sync costs ~40us
// (agent-acquire polls emit L2 invalidates). The kernel boundary is the
// cheapest device-wide barrier. So:
//   K1: per-32-row partial sums SP1/SQ1      (reads h once, writes 1.6 MB)
//   K2: per-block REDUNDANT prefix reduction over predecessor partials
//       (L2-hot, hidden under its own h re-read), within-chunk register
//       scan, emit out straight from registers.

namespace {
constexpr int S    = 8192;
constexpr int D    = 768;
constexpr int DV   = D / 4;       // 192 float4 per row
constexpr int QL   = 64;          // float4-columns per block
constexpr int NG   = DV / QL;     // 3 column groups
constexpr int CH1  = 32;          // K1 rows per partial
constexpr int NC1  = S / CH1;     // 256 partials per group
constexpr int CH2  = 64;          // K2 rows per chunk
constexpr int NC2  = S / CH2;     // 128 chunks
constexpr int RG   = 4;           // waves per block
constexpr int RR1  = CH1 / RG;    // 8 rows per wave (K1)
constexpr int RR2  = CH2 / RG;    // 16 rows per wave (K2)
}

__device__ __forceinline__ float4 f4add(float4 a, float4 b) {
    return make_float4(a.x + b.x, a.y + b.y, a.z + b.z, a.w + b.w);
}
__device__ __forceinline__ void f4relu_fma(float4& acc, float4 h, float d) {
    acc.x += fmaxf(h.x, 0.f) * d;
    acc.y += fmaxf(h.y, 0.f) * d;
    acc.z += fmaxf(h.z, 0.f) * d;
    acc.w += fmaxf(h.w, 0.f) * d;
}

__global__ __launch_bounds__(256)
void heat_partials(const float* __restrict__ h, const float* __restrict__ t,
                   const float* __restrict__ betap,
                   float4* __restrict__ SP1, float4* __restrict__ SQ1) {
    const int tid = threadIdx.x, lane = tid & (QL - 1), r = tid >> 6;
    const int c = blockIdx.x, g = blockIdx.y;
    const int q = g * QL + lane;
    __shared__ float dec[CH1];
    __shared__ float4 rgP[RG][QL], rgQ[RG][QL];
    const float4* h4 = (const float4*)h;
    const int row0 = c * CH1 + r * RR1;
    float4 hv[RR1];
#pragma unroll
    for (int k = 0; k < RR1; ++k) hv[k] = h4[(size_t)(row0 + k) * DV + q];
    if (tid < CH1) dec[tid] = expf(-betap[0] * t[c * CH1 + tid]);
    __syncthreads();
    float4 pp = {0, 0, 0, 0}, qq = {0, 0, 0, 0};
#pragma unroll
    for (int k = 0; k < RR1; ++k) {
        pp = f4add(pp, hv[k]);
        f4relu_fma(qq, hv[k], dec[r * RR1 + k]);
    }
    rgP[r][lane] = pp;
    rgQ[r][lane] = qq;
    __syncthreads();
    if (r == 0) {
        SP1[c * DV + q] = f4add(f4add(rgP[0][lane], rgP[1][lane]),
                                f4add(rgP[2][lane], rgP[3][lane]));
        SQ1[c * DV + q] = f4add(f4add(rgQ[0][lane], rgQ[1][lane]),
                                f4add(rgQ[2][lane], rgQ[3][lane]));
    }
}

__global__ __launch_bounds__(256)
void heat_out(const float* __restrict__ h, const float* __restrict__ t,
              const float* __restrict__ epsp, const float* __restrict__ betap,
              const float4* __restrict__ SP1, const float4* __restrict__ SQ1,
              float* __restrict__ out) {
    const int tid  = threadIdx.x;
    const int lane = tid & (QL - 1);
    const int r    = tid >> 6;          // wave 0..3
    const int c    = blockIdx.x;        // 64-row chunk
    const int g    = blockIdx.y;        // column group
    const int q    = g * QL + lane;
    const float eps = epsp[0], beta = betap[0];

    __shared__ float tt[CH2 + 1];
    __shared__ float dec[CH2], epv[CH2];
    __shared__ float4 rgP[RG][QL], rgQ[RG][QL];
    __shared__ float4 redP[RG][QL], redQ[RG][QL];
    __shared__ float4 prefP[QL], prefQ[QL];

    const float4* h4   = (const float4*)h;
    float4*       out4 = (float4*)out;
    const int row0 = c * CH2 + r * RR2;

    // Issue h loads first; everything below hides under them.
    float4 hv[RR2];
#pragma unroll
    for (int k = 0; k < RR2; ++k) hv[k] = h4[(size_t)(row0 + k) * DV + q];

    if (tid <= CH2) {
        int j = c * CH2 + tid;
        tt[tid] = (j < S) ? t[j] : 1e30f;   // sentinel past the end
    }
    __syncthreads();
    if (tid < CH2) {
        float tv = tt[tid];
        dec[tid] = expf(-beta * tv);
        epv[tid] = eps * expf(beta * tv);
    }

    // Redundant exclusive prefix over predecessor 32-row partials,
    // striped across the 4 waves, 8-deep batched loads (L2-hot).
    const float4 z = {0, 0, 0, 0};
    const int m = 2 * c;                 // partials strictly before this chunk
    float4 aP = z, aQ = z;
    int p = r;
    for (; p + 32 <= m; p += 32) {
        float4 vP[8], vQ[8];
#pragma unroll
        for (int u = 0; u < 8; ++u)
            vP[u] = SP1[((size_t)(p + 4 * u)) * DV + q];
#pragma unroll
        for (int u = 0; u < 8; ++u)
            vQ[u] = SQ1[((size_t)(p + 4 * u)) * DV + q];
#pragma unroll
        for (int u = 0; u < 8; ++u) { aP = f4add(aP, vP[u]); aQ = f4add(aQ, vQ[u]); }
    }
    for (; p < m; p += 4) {
        aP = f4add(aP, SP1[(size_t)p * DV + q]);
        aQ = f4add(aQ, SQ1[(size_t)p * DV + q]);
    }
    redP[r][lane] = aP;
    redQ[r][lane] = aQ;

    // Within-chunk per-wave sums (needs dec -> after the barrier above).
    __syncthreads();
    float4 pp = z, qq = z;
#pragma unroll
    for (int k = 0; k < RR2; ++k) {
        pp = f4add(pp, hv[k]);
        f4relu_fma(qq, hv[k], dec[r * RR2 + k]);
    }
    rgP[r][lane] = pp;
    rgQ[r][lane] = qq;
    if (tid < QL) {
        prefP[lane] = f4add(f4add(redP[0][lane], redP[1][lane]),
                            f4add(redP[2][lane], redP[3][lane]));
    } else if (tid < 2 * QL) {
        prefQ[lane] = f4add(f4add(redQ[0][lane], redQ[1][lane]),
                            f4add(redQ[2][lane], redQ[3][lane]));
    }
    __syncthreads();

    // ---- emit out straight from registers ----
    float4 po = prefP[lane];
    float4 qo = prefQ[lane];
#pragma unroll
    for (int rr2 = 0; rr2 < RG - 1; ++rr2)
        if (rr2 < r) {
            po = f4add(po, rgP[rr2][lane]);
            qo = f4add(qo, rgQ[rr2][lane]);
        }
#pragma unroll
    for (int k = 0; k < RR2; ++k) {
        po = f4add(po, hv[k]);
        f4relu_fma(qo, hv[k], dec[r * RR2 + k]);
        const float ep = epv[r * RR2 + k];
        float4 o;
        o.x = po.x + ep * qo.x;
        o.y = po.y + ep * qo.y;
        o.z = po.z + ep * qo.z;
        o.w = po.w + ep * qo.w;
        const int lr = r * RR2 + k;
        if (tt[lr + 1] == tt[lr]) {          // rare: duplicate-timestamp run
            int j = row0 + k + 1;
            const float tcur = tt[lr];
            float tj = tt[lr + 1];
            while (tj == tcur) {
                float4 hj = h4[(size_t)j * DV + q];
                o.x += hj.x + eps * fmaxf(hj.x, 0.f);
                o.y += hj.y + eps * fmaxf(hj.y, 0.f);
                o.z += hj.z + eps * fmaxf(hj.z, 0.f);
                o.w += hj.w + eps * fmaxf(hj.w, 0.f);
                ++j;
                if (j >= S) break;
                const int lj = j - c * CH2;
                tj = (lj <= CH2) ? tt[lj] : t[j];
            }
        }
        out4[(size_t)(row0 + k) * DV + q] = o;
    }
}

extern "C" void kernel_launch(void* const* d_in, const int* in_sizes, int n_in,
                              void* d_out, int out_size, void* d_ws, size_t ws_size,
                              hipStream_t stream) {
    const float* h    = (const float*)d_in[0];
    const float* t    = (const float*)d_in[1];
    const float* eps  = (const float*)d_in[2];
    const float* beta = (const float*)d_in[3];
    float* out = (float*)d_out;

    float4* SP1 = (float4*)d_ws;               // NC1*DV float4 = 786 KB
    float4* SQ1 = SP1 + (size_t)NC1 * DV;      // 786 KB

    heat_partials<<<dim3(NC1, NG), 256, 0, stream>>>(h, t, beta, SP1, SQ1);
    heat_out<<<dim3(NC2, NG), 256, 0, stream>>>(h, t, eps, beta, SP1, SQ1, out);
}

// Round 8
// 23.849 us; speedup vs baseline: 12.0353x; 1.3299x over previous
//
#include <hip/hip_runtime.h>

// HEAT layer with sorted timestamps — 3 kernels, two-level scan, no atomics.
//   out[i] = P_inc[i] + eps*exp(beta*t_i) * Q_inc[i]   (+ duplicate-t fixup)
//   P_inc[i] = sum_{j<=i} h[j],  Q_inc[i] = sum_{j<=i} relu(h[j])*exp(-beta*t_j)
// Rows j>i with t[j]==t[i] contribute h[j] + eps*relu(h[j]) exactly.
//
// Lessons: r5/r6 — intra-kernel cross-XCD flag sync costs 40-250us (agent
// acquire = L2 invalidate). r7 — full redundant per-block prefix is
// tail-latency-bound (~126 loads/thread for late chunks). Hybrid:
//   K1: 32-row partials SP1/SQ1                      (reads h once)
//   K2: 1024-row super-sums (8 per column group)     (tiny, L2-hot)
//   K3: per-block offset = <=7 supers + <=31 partials (<=19 loads/thread,
//       striped over 4 waves), within-chunk register scan, emit from regs.

namespace {
constexpr int S   = 8192;
constexpr int D   = 768;
constexpr int DV  = D / 4;       // 192 float4 per row
constexpr int QL  = 64;          // float4-columns per block
constexpr int NG  = DV / QL;     // 3 column groups
constexpr int CH  = 32;          // rows per chunk/partial
constexpr int NC  = S / CH;      // 256 partials per column group
constexpr int RG  = 4;           // waves per block
constexpr int RR  = CH / RG;     // 8 rows per wave
constexpr int SUPER = 32;        // partials per super
constexpr int NS  = NC / SUPER;  // 8 supers
}

__device__ __forceinline__ float4 f4add(float4 a, float4 b) {
    return make_float4(a.x + b.x, a.y + b.y, a.z + b.z, a.w + b.w);
}
__device__ __forceinline__ void f4relu_fma(float4& acc, float4 h, float d) {
    acc.x += fmaxf(h.x, 0.f) * d;
    acc.y += fmaxf(h.y, 0.f) * d;
    acc.z += fmaxf(h.z, 0.f) * d;
    acc.w += fmaxf(h.w, 0.f) * d;
}

__global__ __launch_bounds__(256)
void heat_partials(const float* __restrict__ h, const float* __restrict__ t,
                   const float* __restrict__ betap,
                   float4* __restrict__ SP1, float4* __restrict__ SQ1) {
    const int tid = threadIdx.x, lane = tid & (QL - 1), r = tid >> 6;
    const int c = blockIdx.x, g = blockIdx.y;
    const int q = g * QL + lane;
    __shared__ float dec[CH];
    __shared__ float4 rgP[RG][QL], rgQ[RG][QL];
    const float4* h4 = (const float4*)h;
    const int row0 = c * CH + r * RR;
    float4 hv[RR];
#pragma unroll
    for (int k = 0; k < RR; ++k) hv[k] = h4[(size_t)(row0 + k) * DV + q];
    if (tid < CH) dec[tid] = expf(-betap[0] * t[c * CH + tid]);
    __syncthreads();
    float4 pp = {0, 0, 0, 0}, qq = {0, 0, 0, 0};
#pragma unroll
    for (int k = 0; k < RR; ++k) {
        pp = f4add(pp, hv[k]);
        f4relu_fma(qq, hv[k], dec[r * RR + k]);
    }
    rgP[r][lane] = pp;
    rgQ[r][lane] = qq;
    __syncthreads();
    if (r == 0) {
        SP1[c * DV + q] = f4add(f4add(rgP[0][lane], rgP[1][lane]),
                                f4add(rgP[2][lane], rgP[3][lane]));
        SQ1[c * DV + q] = f4add(f4add(rgQ[0][lane], rgQ[1][lane]),
                                f4add(rgQ[2][lane], rgQ[3][lane]));
    }
}

__global__ __launch_bounds__(256)
void heat_supers(const float4* __restrict__ SP1, const float4* __restrict__ SQ1,
                 float4* __restrict__ SuperP, float4* __restrict__ SuperQ) {
    const int tid = threadIdx.x, lane = tid & (QL - 1), w = tid >> 6;
    const int s = blockIdx.x, g = blockIdx.y;
    const int q = g * QL + lane;
    __shared__ float4 redP[RG][QL], redQ[RG][QL];
    const float4 z = {0, 0, 0, 0};
    float4 aP = z, aQ = z;
#pragma unroll
    for (int k = 0; k < SUPER / RG; ++k) {
        int p = s * SUPER + w + k * RG;
        aP = f4add(aP, SP1[(size_t)p * DV + q]);
        aQ = f4add(aQ, SQ1[(size_t)p * DV + q]);
    }
    redP[w][lane] = aP;
    redQ[w][lane] = aQ;
    __syncthreads();
    if (tid < QL)
        SuperP[s * DV + q] = f4add(f4add(redP[0][lane], redP[1][lane]),
                                   f4add(redP[2][lane], redP[3][lane]));
    else if (tid < 2 * QL)
        SuperQ[s * DV + q] = f4add(f4add(redQ[0][lane], redQ[1][lane]),
                                   f4add(redQ[2][lane], redQ[3][lane]));
}

__global__ __launch_bounds__(256)
void heat_out(const float* __restrict__ h, const float* __restrict__ t,
              const float* __restrict__ epsp, const float* __restrict__ betap,
              const float4* __restrict__ SP1, const float4* __restrict__ SQ1,
              const float4* __restrict__ SuperP, const float4* __restrict__ SuperQ,
              float* __restrict__ out) {
    const int tid  = threadIdx.x;
    const int lane = tid & (QL - 1);
    const int r    = tid >> 6;          // wave 0..3
    const int c    = blockIdx.x;        // chunk == partial index
    const int g    = blockIdx.y;        // column group
    const int q    = g * QL + lane;
    const float eps = epsp[0], beta = betap[0];

    __shared__ float tt[CH + 1];
    __shared__ float dec[CH], epv[CH];
    __shared__ float4 rgP[RG][QL], rgQ[RG][QL];
    __shared__ float4 redP[RG][QL], redQ[RG][QL];
    __shared__ float4 prefP[QL], prefQ[QL];

    const float4* h4   = (const float4*)h;
    float4*       out4 = (float4*)out;
    const int row0 = c * CH + r * RR;

    // Bulk h loads first — everything else rides behind them.
    float4 hv[RR];
#pragma unroll
    for (int k = 0; k < RR; ++k) hv[k] = h4[(size_t)(row0 + k) * DV + q];

    // Two-level exclusive offset: <=7 supers + <=31 partials, striped by wave.
    const float4 z = {0, 0, 0, 0};
    const int sup  = c >> 5;            // complete supers before c
    const int base = c & ~(SUPER - 1);  // first partial of current super
    float4 aP = z, aQ = z;
    for (int s2 = r; s2 < sup; s2 += RG) {
        aP = f4add(aP, SuperP[(size_t)s2 * DV + q]);
        aQ = f4add(aQ, SuperQ[(size_t)s2 * DV + q]);
    }
    for (int p = base + r; p < c; p += RG) {
        aP = f4add(aP, SP1[(size_t)p * DV + q]);
        aQ = f4add(aQ, SQ1[(size_t)p * DV + q]);
    }
    redP[r][lane] = aP;
    redQ[r][lane] = aQ;

    if (tid <= CH) {
        int j = c * CH + tid;
        tt[tid] = (j < S) ? t[j] : 1e30f;   // sentinel past the end
    }
    __syncthreads();
    if (tid < CH) {
        float tv = tt[tid];
        dec[tid] = expf(-beta * tv);
        epv[tid] = eps * expf(beta * tv);
    }
    if (tid < QL)
        prefP[lane] = f4add(f4add(redP[0][lane], redP[1][lane]),
                            f4add(redP[2][lane], redP[3][lane]));
    else if (tid < 2 * QL)
        prefQ[lane] = f4add(f4add(redQ[0][lane], redQ[1][lane]),
                            f4add(redQ[2][lane], redQ[3][lane]));
    __syncthreads();

    // Within-chunk per-wave sums.
    float4 pp = z, qq = z;
#pragma unroll
    for (int k = 0; k < RR; ++k) {
        pp = f4add(pp, hv[k]);
        f4relu_fma(qq, hv[k], dec[r * RR + k]);
    }
    rgP[r][lane] = pp;
    rgQ[r][lane] = qq;
    __syncthreads();

    // ---- emit out straight from registers ----
    float4 po = prefP[lane];
    float4 qo = prefQ[lane];
#pragma unroll
    for (int rr2 = 0; rr2 < RG - 1; ++rr2)
        if (rr2 < r) {
            po = f4add(po, rgP[rr2][lane]);
            qo = f4add(qo, rgQ[rr2][lane]);
        }
#pragma unroll
    for (int k = 0; k < RR; ++k) {
        po = f4add(po, hv[k]);
        f4relu_fma(qo, hv[k], dec[r * RR + k]);
        const float ep = epv[r * RR + k];
        float4 o;
        o.x = po.x + ep * qo.x;
        o.y = po.y + ep * qo.y;
        o.z = po.z + ep * qo.z;
        o.w = po.w + ep * qo.w;
        const int lr = r * RR + k;
        if (tt[lr + 1] == tt[lr]) {          // rare: duplicate-timestamp run
            int j = row0 + k + 1;
            const float tcur = tt[lr];
            float tj = tt[lr + 1];
            while (tj == tcur) {
                float4 hj = h4[(size_t)j * DV + q];
                o.x += hj.x + eps * fmaxf(hj.x, 0.f);
                o.y += hj.y + eps * fmaxf(hj.y, 0.f);
                o.z += hj.z + eps * fmaxf(hj.z, 0.f);
                o.w += hj.w + eps * fmaxf(hj.w, 0.f);
                ++j;
                if (j >= S) break;
                const int lj = j - c * CH;
                tj = (lj <= CH) ? tt[lj] : t[j];
            }
        }
        out4[(size_t)(row0 + k) * DV + q] = o;
    }
}

extern "C" void kernel_launch(void* const* d_in, const int* in_sizes, int n_in,
                              void* d_out, int out_size, void* d_ws, size_t ws_size,
                              hipStream_t stream) {
    const float* h    = (const float*)d_in[0];
    const float* t    = (const float*)d_in[1];
    const float* eps  = (const float*)d_in[2];
    const float* beta = (const float*)d_in[3];
    float* out = (float*)d_out;

    float4* SP1    = (float4*)d_ws;                  // NC*DV f4 = 786 KB
    float4* SQ1    = SP1 + (size_t)NC * DV;          // 786 KB
    float4* SuperP = SQ1 + (size_t)NC * DV;          // NS*DV f4 = 24 KB
    float4* SuperQ = SuperP + (size_t)NS * DV;       // 24 KB

    heat_partials<<<dim3(NC, NG), 256, 0, stream>>>(h, t, beta, SP1, SQ1);
    heat_supers<<<dim3(NS, NG), 256, 0, stream>>>(SP1, SQ1, SuperP, SuperQ);
    heat_out<<<dim3(NC, NG), 256, 0, stream>>>(h, t, eps, beta, SP1, SQ1,
                                               SuperP, SuperQ, out);
}

// Round 9
// 19.884 us; speedup vs baseline: 14.4348x; 1.1994x over previous
//
#include <hip/hip_runtime.h>

// HEAT layer with sorted timestamps — 3 kernels, CH=64, no atomics.
//   out[i] = P_inc[i] + eps*exp(beta*t_i) * Q_inc[i]   (+ duplicate-t fixup)
//   P_inc[i] = sum_{j<=i} h[j],  Q_inc[i] = sum_{j<=i} relu(h[j])*exp(-beta*t_j)
// Rows j>i with t[j]==t[i] contribute h[j] + eps*relu(h[j]) exactly.
//
// Lessons: r5/r6 — intra-kernel cross-XCD sync costs 40-250us. r7/r8 —
// redundant per-block prefix pays an L2-BW tax (63+ MB extra) vs a
// dedicated scan kernel that does the work once. So: round-3 structure,
// halved scan (CH=64), nontemporal out stores (keep h L2-resident for K3),
// offset loads hoisted under the h loads.

namespace {
constexpr int S   = 8192;
constexpr int D   = 768;
constexpr int DV  = D / 4;       // 192 float4 per row
constexpr int CH  = 64;          // rows per chunk
constexpr int NC  = S / CH;      // 128 chunks
constexpr int QL  = 64;          // float4-columns per block
constexpr int NG  = DV / QL;     // 3 column groups
constexpr int RG  = 4;           // waves per block
constexpr int RR  = CH / RG;     // 16 rows per wave
constexpr int SEG = 16;          // scan segments
constexpr int CPS = NC / SEG;    // 8 chunks per segment
constexpr int QPB = 16;          // quads per scan block
constexpr int SBP = DV / QPB;    // 12 scan blocks per array
}

typedef float f4raw __attribute__((ext_vector_type(4)));

__device__ __forceinline__ float4 f4add(float4 a, float4 b) {
    return make_float4(a.x + b.x, a.y + b.y, a.z + b.z, a.w + b.w);
}
__device__ __forceinline__ void f4relu_fma(float4& acc, float4 h, float d) {
    acc.x += fmaxf(h.x, 0.f) * d;
    acc.y += fmaxf(h.y, 0.f) * d;
    acc.z += fmaxf(h.z, 0.f) * d;
    acc.w += fmaxf(h.w, 0.f) * d;
}

__global__ __launch_bounds__(256)
void heat_partials(const float* __restrict__ h, const float* __restrict__ t,
                   const float* __restrict__ betap,
                   float4* __restrict__ SP1, float4* __restrict__ SQ1) {
    const int tid = threadIdx.x, lane = tid & (QL - 1), r = tid >> 6;
    const int c = blockIdx.x, g = blockIdx.y;
    const int q = g * QL + lane;
    __shared__ float dec[CH];
    __shared__ float4 rgP[RG][QL], rgQ[RG][QL];
    const float4* h4 = (const float4*)h;
    const int row0 = c * CH + r * RR;
    float4 hv[RR];
#pragma unroll
    for (int k = 0; k < RR; ++k) hv[k] = h4[(size_t)(row0 + k) * DV + q];
    if (tid < CH) dec[tid] = expf(-betap[0] * t[c * CH + tid]);
    __syncthreads();
    float4 pp = {0, 0, 0, 0}, qq = {0, 0, 0, 0};
#pragma unroll
    for (int k = 0; k < RR; ++k) {
        pp = f4add(pp, hv[k]);
        f4relu_fma(qq, hv[k], dec[r * RR + k]);
    }
    rgP[r][lane] = pp;
    rgQ[r][lane] = qq;
    __syncthreads();
    if (r == 0)
        SP1[c * DV + q] = f4add(f4add(rgP[0][lane], rgP[1][lane]),
                                f4add(rgP[2][lane], rgP[3][lane]));
    else if (r == 1)
        SQ1[c * DV + q] = f4add(f4add(rgQ[0][lane], rgQ[1][lane]),
                                f4add(rgQ[2][lane], rgQ[3][lane]));
}

__global__ __launch_bounds__(256)
void heat_scan(const float4* __restrict__ SP1, const float4* __restrict__ SQ1,
               float4* __restrict__ offP, float4* __restrict__ offQ) {
    const int blk = blockIdx.x;
    const bool isQ = blk >= SBP;
    const int lb = isQ ? blk - SBP : blk;
    const float4* src = isQ ? SQ1 : SP1;
    float4*       dst = isQ ? offQ : offP;
    const int qk = threadIdx.x & (QPB - 1);
    const int sg = threadIdx.x >> 4;       // segment 0..15
    const int qs = lb * QPB + qk;          // column quad
    const int c0 = sg * CPS;
    __shared__ float4 ssum[SEG][QPB];
    float4 v[CPS];
#pragma unroll
    for (int u = 0; u < CPS; ++u) v[u] = src[(c0 + u) * DV + qs];
    float4 tot = {0, 0, 0, 0};
#pragma unroll
    for (int u = 0; u < CPS; ++u) tot = f4add(tot, v[u]);
    ssum[sg][qk] = tot;
    __syncthreads();
    float4 run = {0, 0, 0, 0};
    for (int s2 = 0; s2 < SEG - 1; ++s2)
        if (s2 < sg) run = f4add(run, ssum[s2][qk]);
#pragma unroll
    for (int u = 0; u < CPS; ++u) {
        dst[(c0 + u) * DV + qs] = run;
        run = f4add(run, v[u]);
    }
}

__global__ __launch_bounds__(256)
void heat_out(const float* __restrict__ h, const float* __restrict__ t,
              const float* __restrict__ epsp, const float* __restrict__ betap,
              const float4* __restrict__ offP, const float4* __restrict__ offQ,
              float* __restrict__ out) {
    const int tid  = threadIdx.x;
    const int lane = tid & (QL - 1);
    const int r    = tid >> 6;          // wave 0..3
    const int c    = blockIdx.x;        // 64-row chunk
    const int g    = blockIdx.y;        // column group
    const int q    = g * QL + lane;
    const float eps = epsp[0], beta = betap[0];

    __shared__ float tt[CH + 1];
    __shared__ float dec[CH], epv[CH];
    __shared__ float4 rgP[RG][QL], rgQ[RG][QL];

    const float4* h4   = (const float4*)h;
    float4*       out4 = (float4*)out;
    const int row0 = c * CH + r * RR;

    // Bulk h loads first; the independent offset loads ride right behind.
    float4 hv[RR];
#pragma unroll
    for (int k = 0; k < RR; ++k) hv[k] = h4[(size_t)(row0 + k) * DV + q];
    float4 po = offP[(size_t)c * DV + q];
    float4 qo = offQ[(size_t)c * DV + q];

    if (tid <= CH) {
        int j = c * CH + tid;
        tt[tid] = (j < S) ? t[j] : 1e30f;   // sentinel past the end
    }
    __syncthreads();
    if (tid < CH) {
        float tv = tt[tid];
        dec[tid] = expf(-beta * tv);
        epv[tid] = eps * expf(beta * tv);
    }
    __syncthreads();

    // Within-chunk per-wave sums.
    const float4 z = {0, 0, 0, 0};
    float4 pp = z, qq = z;
#pragma unroll
    for (int k = 0; k < RR; ++k) {
        pp = f4add(pp, hv[k]);
        f4relu_fma(qq, hv[k], dec[r * RR + k]);
    }
    rgP[r][lane] = pp;
    rgQ[r][lane] = qq;
    __syncthreads();

    // Exclusive prefix for this wave's first row.
#pragma unroll
    for (int rr2 = 0; rr2 < RG - 1; ++rr2)
        if (rr2 < r) {
            po = f4add(po, rgP[rr2][lane]);
            qo = f4add(qo, rgQ[rr2][lane]);
        }

    // ---- emit out straight from registers (nontemporal stores) ----
#pragma unroll
    for (int k = 0; k < RR; ++k) {
        po = f4add(po, hv[k]);
        f4relu_fma(qo, hv[k], dec[r * RR + k]);
        const float ep = epv[r * RR + k];
        float4 o;
        o.x = po.x + ep * qo.x;
        o.y = po.y + ep * qo.y;
        o.z = po.z + ep * qo.z;
        o.w = po.w + ep * qo.w;
        const int lr = r * RR + k;
        if (tt[lr + 1] == tt[lr]) {          // rare: duplicate-timestamp run
            int j = row0 + k + 1;
            const float tcur = tt[lr];
            float tj = tt[lr + 1];
            while (tj == tcur) {
                float4 hj = h4[(size_t)j * DV + q];
                o.x += hj.x + eps * fmaxf(hj.x, 0.f);
                o.y += hj.y + eps * fmaxf(hj.y, 0.f);
                o.z += hj.z + eps * fmaxf(hj.z, 0.f);
                o.w += hj.w + eps * fmaxf(hj.w, 0.f);
                ++j;
                if (j >= S) break;
                const int lj = j - c * CH;
                tj = (lj <= CH) ? tt[lj] : t[j];
            }
        }
        __builtin_nontemporal_store(*(const f4raw*)&o,
            (f4raw*)(out4 + (size_t)(row0 + k) * DV + q));
    }
}

extern "C" void kernel_launch(void* const* d_in, const int* in_sizes, int n_in,
                              void* d_out, int out_size, void* d_ws, size_t ws_size,
                              hipStream_t stream) {
    const float* h    = (const float*)d_in[0];
    const float* t    = (const float*)d_in[1];
    const float* eps  = (const float*)d_in[2];
    const float* beta = (const float*)d_in[3];
    float* out = (float*)d_out;

    float4* SP1  = (float4*)d_ws;                 // NC*DV f4 = 393 KB
    float4* SQ1  = SP1 + (size_t)NC * DV;
    float4* offP = SQ1 + (size_t)NC * DV;
    float4* offQ = offP + (size_t)NC * DV;

    heat_partials<<<dim3(NC, NG), 256, 0, stream>>>(h, t, beta, SP1, SQ1);
    heat_scan<<<2 * SBP, 256, 0, stream>>>(SP1, SQ1, offP, offQ);
    heat_out<<<dim3(NC, NG), 256, 0, stream>>>(h, t, eps, beta, offP, offQ, out);
}

// Round 10
// 19.604 us; speedup vs baseline: 14.6407x; 1.0143x over previous
//
#include <hip/hip_runtime.h>

// HEAT layer with sorted timestamps — 3 kernels, CH=64, QL=32 (768 blocks).
//   out[i] = P_inc[i] + eps*exp(beta*t_i) * Q_inc[i]   (+ duplicate-t fixup)
//   P_inc[i] = sum_{j<=i} h[j],  Q_inc[i] = sum_{j<=i} relu(h[j])*exp(-beta*t_j)
// Rows j>i with t[j]==t[i] contribute h[j] + eps*relu(h[j]) exactly.
//
// Lessons: r5/r6 — intra-kernel cross-XCD sync costs 40-250us. r7/r8 —
// redundant per-block prefix pays an L2-BW tax; scan once in a dedicated
// kernel. r9 — NT out stores + small scan + hoisted offsets -> 19.9us.
// r10: 384 -> 768 blocks (QL=32) for 3 blocks/CU: latency hiding was the
// remaining limiter (Occupancy ~14%).

namespace {
constexpr int S   = 8192;
constexpr int D   = 768;
constexpr int DV  = D / 4;       // 192 float4 per row
constexpr int CH  = 64;          // rows per chunk
constexpr int NC  = S / CH;      // 128 chunks
constexpr int QL  = 32;          // float4-columns per block
constexpr int NG  = DV / QL;     // 6 column groups
constexpr int RG  = 8;           // row-groups per block
constexpr int RR  = CH / RG;     // 8 rows per row-group
constexpr int SEG = 16;          // scan segments
constexpr int CPS = NC / SEG;    // 8 chunks per segment
constexpr int QPB = 16;          // quads per scan block
constexpr int SBP = DV / QPB;    // 12 scan blocks per array
}

typedef float f4raw __attribute__((ext_vector_type(4)));

__device__ __forceinline__ float4 f4add(float4 a, float4 b) {
    return make_float4(a.x + b.x, a.y + b.y, a.z + b.z, a.w + b.w);
}
__device__ __forceinline__ void f4relu_fma(float4& acc, float4 h, float d) {
    acc.x += fmaxf(h.x, 0.f) * d;
    acc.y += fmaxf(h.y, 0.f) * d;
    acc.z += fmaxf(h.z, 0.f) * d;
    acc.w += fmaxf(h.w, 0.f) * d;
}

__global__ __launch_bounds__(256)
void heat_partials(const float* __restrict__ h, const float* __restrict__ t,
                   const float* __restrict__ betap,
                   float4* __restrict__ SP1, float4* __restrict__ SQ1) {
    const int tid = threadIdx.x, lane = tid & (QL - 1), r = tid / QL;
    const int c = blockIdx.x, g = blockIdx.y;
    const int q = g * QL + lane;
    __shared__ float dec[CH];
    __shared__ float4 rgP[RG][QL], rgQ[RG][QL];
    const float4* h4 = (const float4*)h;
    const int row0 = c * CH + r * RR;
    float4 hv[RR];
#pragma unroll
    for (int k = 0; k < RR; ++k) hv[k] = h4[(size_t)(row0 + k) * DV + q];
    if (tid < CH) dec[tid] = expf(-betap[0] * t[c * CH + tid]);
    __syncthreads();
    float4 pp = {0, 0, 0, 0}, qq = {0, 0, 0, 0};
#pragma unroll
    for (int k = 0; k < RR; ++k) {
        pp = f4add(pp, hv[k]);
        f4relu_fma(qq, hv[k], dec[r * RR + k]);
    }
    rgP[r][lane] = pp;
    rgQ[r][lane] = qq;
    __syncthreads();
    if (r == 0) {
        float4 sp = rgP[0][lane];
#pragma unroll
        for (int w = 1; w < RG; ++w) sp = f4add(sp, rgP[w][lane]);
        SP1[c * DV + q] = sp;
    } else if (r == 1) {
        float4 sq = rgQ[0][lane];
#pragma unroll
        for (int w = 1; w < RG; ++w) sq = f4add(sq, rgQ[w][lane]);
        SQ1[c * DV + q] = sq;
    }
}

__global__ __launch_bounds__(256)
void heat_scan(const float4* __restrict__ SP1, const float4* __restrict__ SQ1,
               float4* __restrict__ offP, float4* __restrict__ offQ) {
    const int blk = blockIdx.x;
    const bool isQ = blk >= SBP;
    const int lb = isQ ? blk - SBP : blk;
    const float4* src = isQ ? SQ1 : SP1;
    float4*       dst = isQ ? offQ : offP;
    const int qk = threadIdx.x & (QPB - 1);
    const int sg = threadIdx.x >> 4;       // segment 0..15
    const int qs = lb * QPB + qk;          // column quad
    const int c0 = sg * CPS;
    __shared__ float4 ssum[SEG][QPB];
    float4 v[CPS];
#pragma unroll
    for (int u = 0; u < CPS; ++u) v[u] = src[(c0 + u) * DV + qs];
    float4 tot = {0, 0, 0, 0};
#pragma unroll
    for (int u = 0; u < CPS; ++u) tot = f4add(tot, v[u]);
    ssum[sg][qk] = tot;
    __syncthreads();
    float4 run = {0, 0, 0, 0};
    for (int s2 = 0; s2 < SEG - 1; ++s2)
        if (s2 < sg) run = f4add(run, ssum[s2][qk]);
#pragma unroll
    for (int u = 0; u < CPS; ++u) {
        dst[(c0 + u) * DV + qs] = run;
        run = f4add(run, v[u]);
    }
}

__global__ __launch_bounds__(256)
void heat_out(const float* __restrict__ h, const float* __restrict__ t,
              const float* __restrict__ epsp, const float* __restrict__ betap,
              const float4* __restrict__ offP, const float4* __restrict__ offQ,
              float* __restrict__ out) {
    const int tid  = threadIdx.x;
    const int lane = tid & (QL - 1);
    const int r    = tid / QL;          // row-group 0..7
    const int c    = blockIdx.x;        // 64-row chunk
    const int g    = blockIdx.y;        // column group
    const int q    = g * QL + lane;
    const float eps = epsp[0], beta = betap[0];

    __shared__ float tt[CH + 1];
    __shared__ float dec[CH], epv[CH];
    __shared__ float4 rgP[RG][QL], rgQ[RG][QL];

    const float4* h4   = (const float4*)h;
    float4*       out4 = (float4*)out;
    const int row0 = c * CH + r * RR;

    // Bulk h loads first; the independent offset loads ride right behind.
    float4 hv[RR];
#pragma unroll
    for (int k = 0; k < RR; ++k) hv[k] = h4[(size_t)(row0 + k) * DV + q];
    float4 po = offP[(size_t)c * DV + q];
    float4 qo = offQ[(size_t)c * DV + q];

    if (tid <= CH) {
        int j = c * CH + tid;
        tt[tid] = (j < S) ? t[j] : 1e30f;   // sentinel past the end
    }
    __syncthreads();
    if (tid < CH) {
        float tv = tt[tid];
        dec[tid] = expf(-beta * tv);
        epv[tid] = eps * expf(beta * tv);
    }
    __syncthreads();

    // Within-chunk per-row-group sums.
    const float4 z = {0, 0, 0, 0};
    float4 pp = z, qq = z;
#pragma unroll
    for (int k = 0; k < RR; ++k) {
        pp = f4add(pp, hv[k]);
        f4relu_fma(qq, hv[k], dec[r * RR + k]);
    }
    rgP[r][lane] = pp;
    rgQ[r][lane] = qq;
    __syncthreads();

    // Exclusive prefix for this row-group's first row.
#pragma unroll
    for (int rr2 = 0; rr2 < RG - 1; ++rr2)
        if (rr2 < r) {
            po = f4add(po, rgP[rr2][lane]);
            qo = f4add(qo, rgQ[rr2][lane]);
        }

    // ---- emit out straight from registers (nontemporal stores) ----
#pragma unroll
    for (int k = 0; k < RR; ++k) {
        po = f4add(po, hv[k]);
        f4relu_fma(qo, hv[k], dec[r * RR + k]);
        const float ep = epv[r * RR + k];
        float4 o;
        o.x = po.x + ep * qo.x;
        o.y = po.y + ep * qo.y;
        o.z = po.z + ep * qo.z;
        o.w = po.w + ep * qo.w;
        const int lr = r * RR + k;
        if (tt[lr + 1] == tt[lr]) {          // rare: duplicate-timestamp run
            int j = row0 + k + 1;
            const float tcur = tt[lr];
            float tj = tt[lr + 1];
            while (tj == tcur) {
                float4 hj = h4[(size_t)j * DV + q];
                o.x += hj.x + eps * fmaxf(hj.x, 0.f);
                o.y += hj.y + eps * fmaxf(hj.y, 0.f);
                o.z += hj.z + eps * fmaxf(hj.z, 0.f);
                o.w += hj.w + eps * fmaxf(hj.w, 0.f);
                ++j;
                if (j >= S) break;
                const int lj = j - c * CH;
                tj = (lj <= CH) ? tt[lj] : t[j];
            }
        }
        __builtin_nontemporal_store(*(const f4raw*)&o,
            (f4raw*)(out4 + (size_t)(row0 + k) * DV + q));
    }
}

extern "C" void kernel_launch(void* const* d_in, const int* in_sizes, int n_in,
                              void* d_out, int out_size, void* d_ws, size_t ws_size,
                              hipStream_t stream) {
    const float* h    = (const float*)d_in[0];
    const float* t    = (const float*)d_in[1];
    const float* eps  = (const float*)d_in[2];
    const float* beta = (const float*)d_in[3];
    float* out = (float*)d_out;

    float4* SP1  = (float4*)d_ws;                 // NC*DV f4 = 393 KB
    float4* SQ1  = SP1 + (size_t)NC * DV;
    float4* offP = SQ1 + (size_t)NC * DV;
    float4* offQ = offP + (size_t)NC * DV;

    heat_partials<<<dim3(NC, NG), 256, 0, stream>>>(h, t, beta, SP1, SQ1);
    heat_scan<<<2 * SBP, 256, 0, stream>>>(SP1, SQ1, offP, offQ);
    heat_out<<<dim3(NC, NG), 256, 0, stream>>>(h, t, eps, beta, offP, offQ, out);
}